// Round 1
// baseline (814.644 us; speedup 1.0000x reference)
//
#include <hip/hip_runtime.h>

// Problem constants (from reference)
#define HH 4096
#define WW 4096
#define NB 1024
#define NCHUNK 32
#define CROWS (HH / NCHUNK) // 128 rows per chunk
#define IOU_T 0.5f

// ---------------- workspace layout (all sizes multiples of 4096 B) ----------
constexpr size_t OFF_COORDS = 0;                                  // int4 x NB
constexpr size_t OFF_FLAGS  = OFF_COORDS + (size_t)NB * 16;       // int x HH
constexpr size_t OFF_SLOT   = OFF_FLAGS  + (size_t)HH * 4;        // int x HH
constexpr size_t OFF_PART   = OFF_SLOT   + (size_t)HH * 4;        // double x NCHUNK*WW
constexpr size_t OFF_SC64   = OFF_PART   + (size_t)NCHUNK * WW * 8;
constexpr size_t OFF_SC32   = OFF_SC64   + (size_t)NB * 8;
constexpr size_t OFF_ORDER  = OFF_SC32   + (size_t)NB * 4;
constexpr size_t OFF_BS     = OFF_ORDER  + (size_t)NB * 4;        // float4 x NB (sorted boxes)
constexpr size_t OFF_SSD    = OFF_BS     + (size_t)NB * 16;       // double x NB (sorted scores)
constexpr size_t OFF_SS32   = OFF_SSD    + (size_t)NB * 8;        // float x NB
constexpr size_t OFF_IOU    = OFF_SS32   + (size_t)NB * 4;        // u64 x NB*16
constexpr size_t OFF_RECSC  = OFF_IOU    + (size_t)NB * 16 * 8;   // double x NB
constexpr size_t OFF_RECFL  = OFF_RECSC  + (size_t)NB * 8;        // int x NB
constexpr size_t OFF_RECSEL = OFF_RECFL  + (size_t)NB * 4;        // u64 x NB*16
constexpr size_t OFF_CC     = OFF_RECSEL + (size_t)NB * 16 * 8;   // float x 2048*WW
// total ~= 35.0 MB

// ---------------- kernels ---------------------------------------------------

__global__ void k_flags_zero(int* flags) {
    int i = blockIdx.x * blockDim.x + threadIdx.x;
    if (i < HH) flags[i] = 0;
}

__global__ void k_coords(const float* __restrict__ bbox, int4* coords, int* flags) {
    int i = blockIdx.x * blockDim.x + threadIdx.x;
    if (i >= NB) return;
    float b0 = bbox[i * 4 + 0], b1 = bbox[i * 4 + 1];
    float b2 = bbox[i * 4 + 2], b3 = bbox[i * 4 + 3];
    int x1 = min(max((int)floorf(b0), 0), WW);
    int y1 = min(max((int)floorf(b1), 0), HH);
    int x2 = min(max((int)floorf(b2), 0), WW);
    int y2 = min(max((int)floorf(b3), 0), HH);
    coords[i] = make_int4(x1, y1, x2, y2);
    if (y1 >= 1) flags[y1 - 1] = 1;   // benign races: same value
    if (y2 >= 1) flags[y2 - 1] = 1;
}

// exclusive scan of flags -> slot (compact row index for flagged rows)
__global__ void k_scan(const int* __restrict__ flags, int* slot) {
    __shared__ int psum[256];
    int t = threadIdx.x;
    int base = t * 16;
    int s = 0;
    for (int k = 0; k < 16; k++) s += flags[base + k];
    psum[t] = s;
    __syncthreads();
    if (t == 0) {
        int acc = 0;
        for (int k = 0; k < 256; k++) { int v = psum[k]; psum[k] = acc; acc += v; }
    }
    __syncthreads();
    int run = psum[t];
    for (int k = 0; k < 16; k++) { slot[base + k] = run; run += flags[base + k]; }
}

// per-chunk column partial sums (fp64)
__global__ void k_partials(const float* __restrict__ probs, double* __restrict__ part) {
    int tid = blockIdx.x * blockDim.x + threadIdx.x; // NCHUNK*WW threads
    int c = tid >> 12;           // chunk (WW == 4096)
    int x = tid & (WW - 1);
    const float* p = probs + (size_t)c * CROWS * WW + x;
    double acc = 0.0;
    #pragma unroll 4
    for (int r = 0; r < CROWS; r++) acc += (double)p[(size_t)r * WW];
    part[tid] = acc;
}

// second sweep: carry chunk offset, emit fp32 column-cumsum at flagged rows
__global__ void k_sweep(const float* __restrict__ probs, const double* __restrict__ part,
                        const int* __restrict__ flags, const int* __restrict__ slot,
                        float* __restrict__ Cc) {
    int tid = blockIdx.x * blockDim.x + threadIdx.x;
    int c = tid >> 12;
    int x = tid & (WW - 1);
    double acc = 0.0;
    for (int cc = 0; cc < c; cc++) acc += part[(cc << 12) + x];
    const float* p = probs + (size_t)c * CROWS * WW + x;
    int r0 = c * CROWS;
    for (int r = 0; r < CROWS; r++) {
        acc += (double)p[(size_t)r * WW];
        if (flags[r0 + r]) Cc[(size_t)slot[r0 + r] * WW + x] = (float)acc;
    }
}

// per-box rectangle sum via column-cumsum row differences (fp64 accumulate)
__global__ void k_boxsum(const int4* __restrict__ coords, const float* __restrict__ obj,
                         const int* __restrict__ slot, const float* __restrict__ Cc,
                         double* sc64, float* sc32) {
    int i = blockIdx.x * blockDim.x + threadIdx.x;
    if (i >= NB) return;
    int4 cd = coords[i]; // x=x1, y=y1, z=x2, w=y2
    const float* r1 = (cd.y >= 1) ? (Cc + (size_t)slot[cd.y - 1] * WW) : nullptr;
    const float* r2 = (cd.w >= 1) ? (Cc + (size_t)slot[cd.w - 1] * WW) : nullptr;
    double s = 0.0;
    for (int x = cd.x; x < cd.z; x++) {
        double v2 = r2 ? (double)r2[x] : 0.0;
        double v1 = r1 ? (double)r1[x] : 0.0;
        s += (v2 - v1);
    }
    long long cnt = (long long)(cd.w - cd.y) * (long long)(cd.z - cd.x);
    if (cnt < 1) cnt = 1;
    double box = s / (double)cnt;
    double sc = 0.5 * ((double)obj[i] + box);
    sc64[i] = sc;
    sc32[i] = (float)sc;
}

// stable descending rank sort: rank = #{j : s_j > s_i or (s_j == s_i and j < i)}
__global__ void k_rank(const double* __restrict__ sc64, int* order) {
    __shared__ double s[NB];
    int t = threadIdx.x; // 256 threads, 1 block
    for (int k = t; k < NB; k += 256) s[k] = sc64[k];
    __syncthreads();
    for (int i = t; i < NB; i += 256) {
        double si = s[i];
        int rank = 0;
        for (int j = 0; j < NB; j++) {
            double sj = s[j];
            rank += (sj > si) || (sj == si && j < i);
        }
        order[rank] = i;
    }
}

__global__ void k_gather(const int* __restrict__ order, const float* __restrict__ bbox,
                         const double* __restrict__ sc64, const float* __restrict__ sc32,
                         float4* bs, double* ssd, float* ss32) {
    int i = blockIdx.x * blockDim.x + threadIdx.x;
    if (i >= NB) return;
    int o = order[i];
    bs[i] = ((const float4*)bbox)[o];
    ssd[i] = sc64[o];
    ss32[i] = sc32[o];
}

// IoU(bs_i, bs_j) > 0.5 bit matrix, one u64 word per 64 j's via ballot
__global__ void k_iou(const float4* __restrict__ bs, unsigned long long* __restrict__ ioub) {
    int tid = blockIdx.x * blockDim.x + threadIdx.x; // NB*NB threads
    int i = tid >> 10;
    int j = tid & (NB - 1);
    float4 a = bs[i], b = bs[j];
    float ai = (a.z - a.x) * (a.w - a.y);
    float aj = (b.z - b.x) * (b.w - b.y);
    float ix1 = fmaxf(a.x, b.x), iy1 = fmaxf(a.y, b.y);
    float ix2 = fminf(a.z, b.z), iy2 = fminf(a.w, b.w);
    float iw = fmaxf(ix2 - ix1, 0.0f), ih = fmaxf(iy2 - iy1, 0.0f);
    float inter = iw * ih;
    float iou_v = inter / (ai + aj - inter);
    bool bit = iou_v > IOU_T;
    unsigned long long m = __ballot(bit);
    if ((threadIdx.x & 63) == 0) ioub[(size_t)i * 16 + (j >> 6)] = m;
}

// greedy grouping, one thread per start; incompat union mask in LDS.
// Exact check-before-add semantics of the reference scan.
__global__ void __launch_bounds__(128) k_group(const unsigned long long* __restrict__ ioub,
                                               const double* __restrict__ ssd,
                                               const int* __restrict__ counts,
                                               int* recfl, double* recsc,
                                               unsigned long long* recsel) {
    __shared__ unsigned long long inc[128][17];
    __shared__ unsigned long long sel[128][17];
    int t = threadIdx.x;
    int i = blockIdx.x * blockDim.x + t;
    int K = counts[0];
    for (int w = 0; w < 16; w++) {
        inc[t][w] = ioub[(size_t)i * 16 + w];
        sel[t][w] = 0ULL;
    }
    sel[t][i >> 6] = 1ULL << (i & 63);
    int size = 1;
    double score = ssd[i];
    int rec = 0;
    for (int j = i + 1; j < NB; j++) {
        if (size == K) { rec = 1; break; }   // record at TOP of iteration j
        if (!((inc[t][j >> 6] >> (j & 63)) & 1ULL)) {
            sel[t][j >> 6] |= 1ULL << (j & 63);
            size++;
            score += ssd[j];
            const unsigned long long* rj = ioub + (size_t)j * 16;
            for (int w = 0; w < 16; w++) inc[t][w] |= rj[w];
        }
    }
    recfl[i] = rec;
    recsc[i] = rec ? score : -1e300;
    for (int w = 0; w < 16; w++) recsel[(size_t)i * 16 + w] = sel[t][w];
}

// best = max recorded score, ties -> LAST index (reference's last-argmax rule)
__global__ void k_final(const double* __restrict__ recsc,
                        const unsigned long long* __restrict__ recsel,
                        const float* __restrict__ ss32, float* __restrict__ out) {
    __shared__ double bsc[NB];
    __shared__ int bidx[NB];
    int t = threadIdx.x; // 1024 threads
    bsc[t] = recsc[t];
    bidx[t] = t;
    __syncthreads();
    for (int s = 512; s > 0; s >>= 1) {
        if (t < s) {
            double a = bsc[t], b = bsc[t + s];
            if (b > a || (b == a && bidx[t + s] > bidx[t])) {
                bsc[t] = b;
                bidx[t] = bidx[t + s];
            }
        }
        __syncthreads();
    }
    __shared__ int best, any;
    if (t == 0) { best = bidx[0]; any = (bsc[0] > -1e299) ? 1 : 0; }
    __syncthreads();
    float v = 0.0f;
    if (any) {
        if ((recsel[(size_t)best * 16 + (t >> 6)] >> (t & 63)) & 1ULL) v = ss32[t];
    }
    out[t] = v;
}

// ---------------- host entry ------------------------------------------------

extern "C" void kernel_launch(void* const* d_in, const int* in_sizes, int n_in,
                              void* d_out, int out_size, void* d_ws, size_t ws_size,
                              hipStream_t stream) {
    const float* bbox  = (const float*)d_in[0];
    const float* obj   = (const float*)d_in[1];
    const float* probs = (const float*)d_in[2];
    const int*   counts = (const int*)d_in[3];
    float* out = (float*)d_out;

    char* w = (char*)d_ws;
    int4*   coords = (int4*)(w + OFF_COORDS);
    int*    flags  = (int*)(w + OFF_FLAGS);
    int*    slot   = (int*)(w + OFF_SLOT);
    double* part   = (double*)(w + OFF_PART);
    double* sc64   = (double*)(w + OFF_SC64);
    float*  sc32   = (float*)(w + OFF_SC32);
    int*    order  = (int*)(w + OFF_ORDER);
    float4* bs     = (float4*)(w + OFF_BS);
    double* ssd    = (double*)(w + OFF_SSD);
    float*  ss32   = (float*)(w + OFF_SS32);
    unsigned long long* ioub   = (unsigned long long*)(w + OFF_IOU);
    double* recsc  = (double*)(w + OFF_RECSC);
    int*    recfl  = (int*)(w + OFF_RECFL);
    unsigned long long* recsel = (unsigned long long*)(w + OFF_RECSEL);
    float*  Cc     = (float*)(w + OFF_CC);

    k_flags_zero<<<HH / 256, 256, 0, stream>>>(flags);
    k_coords<<<NB / 256, 256, 0, stream>>>(bbox, coords, flags);
    k_scan<<<1, 256, 0, stream>>>(flags, slot);
    k_partials<<<(NCHUNK * WW) / 256, 256, 0, stream>>>(probs, part);
    k_sweep<<<(NCHUNK * WW) / 256, 256, 0, stream>>>(probs, part, flags, slot, Cc);
    k_boxsum<<<NB / 256, 256, 0, stream>>>(coords, obj, slot, Cc, sc64, sc32);
    k_rank<<<1, 256, 0, stream>>>(sc64, order);
    k_gather<<<NB / 256, 256, 0, stream>>>(order, bbox, sc64, sc32, bs, ssd, ss32);
    k_iou<<<(NB * NB) / 256, 256, 0, stream>>>(bs, ioub);
    k_group<<<NB / 128, 128, 0, stream>>>(ioub, ssd, counts, recfl, recsc, recsel);
    k_final<<<1, 1024, 0, stream>>>(recsc, recsel, ss32, out);
}

// Round 2
// 244.853 us; speedup vs baseline: 3.3271x; 3.3271x over previous
//
#include <hip/hip_runtime.h>

// Problem constants (from reference)
#define HH 4096
#define WW 4096
#define NB 1024
#define NCHUNK 32
#define CROWS (HH / NCHUNK) // 128 rows per chunk
#define IOU_T 0.5f

// ---------------- workspace layout (all sizes multiples of 4096 B) ----------
constexpr size_t OFF_COORDS = 0;                                  // int4 x NB
constexpr size_t OFF_FLAGS  = OFF_COORDS + (size_t)NB * 16;       // int x HH
constexpr size_t OFF_SLOT   = OFF_FLAGS  + (size_t)HH * 4;        // int x HH
constexpr size_t OFF_PART   = OFF_SLOT   + (size_t)HH * 4;        // double x NCHUNK*WW
constexpr size_t OFF_SC64   = OFF_PART   + (size_t)NCHUNK * WW * 8;
constexpr size_t OFF_SC32   = OFF_SC64   + (size_t)NB * 8;
constexpr size_t OFF_ORDER  = OFF_SC32   + (size_t)NB * 4;
constexpr size_t OFF_BS     = OFF_ORDER  + (size_t)NB * 4;        // float4 x NB (sorted boxes)
constexpr size_t OFF_SSD    = OFF_BS     + (size_t)NB * 16;       // double x NB (sorted scores)
constexpr size_t OFF_SS32   = OFF_SSD    + (size_t)NB * 8;        // float x NB
constexpr size_t OFF_IOU    = OFF_SS32   + (size_t)NB * 4;        // u64 x NB*16
constexpr size_t OFF_RECSC  = OFF_IOU    + (size_t)NB * 16 * 8;   // double x NB
constexpr size_t OFF_RECFL  = OFF_RECSC  + (size_t)NB * 8;        // int x NB
constexpr size_t OFF_RECSEL = OFF_RECFL  + (size_t)NB * 4;        // u64 x NB*16
constexpr size_t OFF_CC     = OFF_RECSEL + (size_t)NB * 16 * 8;   // float x 2048*WW
// total ~= 35.0 MB

// ---------------- kernels ---------------------------------------------------

__global__ void k_flags_zero(int* flags) {
    int i = blockIdx.x * blockDim.x + threadIdx.x;
    if (i < HH) flags[i] = 0;
}

__global__ void k_coords(const float* __restrict__ bbox, int4* coords, int* flags) {
    int i = blockIdx.x * blockDim.x + threadIdx.x;
    if (i >= NB) return;
    float b0 = bbox[i * 4 + 0], b1 = bbox[i * 4 + 1];
    float b2 = bbox[i * 4 + 2], b3 = bbox[i * 4 + 3];
    int x1 = min(max((int)floorf(b0), 0), WW);
    int y1 = min(max((int)floorf(b1), 0), HH);
    int x2 = min(max((int)floorf(b2), 0), WW);
    int y2 = min(max((int)floorf(b3), 0), HH);
    coords[i] = make_int4(x1, y1, x2, y2);
    if (y1 >= 1) flags[y1 - 1] = 1;   // benign races: same value
    if (y2 >= 1) flags[y2 - 1] = 1;
}

// exclusive scan of flags -> slot (compact row index for flagged rows)
__global__ void k_scan(const int* __restrict__ flags, int* slot) {
    __shared__ int psum[256];
    int t = threadIdx.x;
    int base = t * 16;
    int s = 0;
    for (int k = 0; k < 16; k++) s += flags[base + k];
    psum[t] = s;
    __syncthreads();
    if (t == 0) {
        int acc = 0;
        for (int k = 0; k < 256; k++) { int v = psum[k]; psum[k] = acc; acc += v; }
    }
    __syncthreads();
    int run = psum[t];
    for (int k = 0; k < 16; k++) { slot[base + k] = run; run += flags[base + k]; }
}

// per-chunk column partial sums (fp64)
__global__ void k_partials(const float* __restrict__ probs, double* __restrict__ part) {
    int tid = blockIdx.x * blockDim.x + threadIdx.x; // NCHUNK*WW threads
    int c = tid >> 12;           // chunk (WW == 4096)
    int x = tid & (WW - 1);
    const float* p = probs + (size_t)c * CROWS * WW + x;
    double acc = 0.0;
    #pragma unroll 4
    for (int r = 0; r < CROWS; r++) acc += (double)p[(size_t)r * WW];
    part[tid] = acc;
}

// second sweep: carry chunk offset, emit fp32 column-cumsum at flagged rows
__global__ void k_sweep(const float* __restrict__ probs, const double* __restrict__ part,
                        const int* __restrict__ flags, const int* __restrict__ slot,
                        float* __restrict__ Cc) {
    int tid = blockIdx.x * blockDim.x + threadIdx.x;
    int c = tid >> 12;
    int x = tid & (WW - 1);
    double acc = 0.0;
    for (int cc = 0; cc < c; cc++) acc += part[(cc << 12) + x];
    const float* p = probs + (size_t)c * CROWS * WW + x;
    int r0 = c * CROWS;
    for (int r = 0; r < CROWS; r++) {
        acc += (double)p[(size_t)r * WW];
        if (flags[r0 + r]) Cc[(size_t)slot[r0 + r] * WW + x] = (float)acc;
    }
}

// per-box rectangle sum: ONE WAVE PER BOX, lanes stride columns, fp64
// shuffle-reduce. (R1: 1 thread/box serial loop was 512 us at 0.18% occupancy.)
__global__ void __launch_bounds__(64) k_boxsum(const int4* __restrict__ coords,
                         const float* __restrict__ obj,
                         const int* __restrict__ slot, const float* __restrict__ Cc,
                         double* sc64, float* sc32) {
    int i = blockIdx.x;       // one 64-lane block per box
    int lane = threadIdx.x;
    int4 cd = coords[i]; // x=x1, y=y1, z=x2, w=y2
    const float* r1 = (cd.y >= 1) ? (Cc + (size_t)slot[cd.y - 1] * WW) : nullptr;
    const float* r2 = (cd.w >= 1) ? (Cc + (size_t)slot[cd.w - 1] * WW) : nullptr;
    double s = 0.0;
    for (int x = cd.x + lane; x < cd.z; x += 64) {
        double v2 = r2 ? (double)r2[x] : 0.0;
        double v1 = r1 ? (double)r1[x] : 0.0;
        s += (v2 - v1);
    }
    #pragma unroll
    for (int off = 32; off > 0; off >>= 1) s += __shfl_down(s, off);
    if (lane == 0) {
        long long cnt = (long long)(cd.w - cd.y) * (long long)(cd.z - cd.x);
        if (cnt < 1) cnt = 1;
        double box = s / (double)cnt;
        double sc = 0.5 * ((double)obj[i] + box);
        sc64[i] = sc;
        sc32[i] = (float)sc;
    }
}

// stable descending rank sort: rank = #{j : s_j > s_i or (s_j == s_i and j < i)}
// 4 blocks x 256 threads, scores cached in LDS per block.
__global__ void k_rank(const double* __restrict__ sc64, int* order) {
    __shared__ double s[NB];
    int t = threadIdx.x;
    for (int k = t; k < NB; k += 256) s[k] = sc64[k];
    __syncthreads();
    int i = blockIdx.x * 256 + t;
    double si = s[i];
    int rank = 0;
    for (int j = 0; j < NB; j++) {
        double sj = s[j];
        rank += (sj > si) || (sj == si && j < i);
    }
    order[rank] = i;
}

__global__ void k_gather(const int* __restrict__ order, const float* __restrict__ bbox,
                         const double* __restrict__ sc64, const float* __restrict__ sc32,
                         float4* bs, double* ssd, float* ss32) {
    int i = blockIdx.x * blockDim.x + threadIdx.x;
    if (i >= NB) return;
    int o = order[i];
    bs[i] = ((const float4*)bbox)[o];
    ssd[i] = sc64[o];
    ss32[i] = sc32[o];
}

// IoU(bs_i, bs_j) > 0.5 bit matrix, one u64 word per 64 j's via ballot
__global__ void k_iou(const float4* __restrict__ bs, unsigned long long* __restrict__ ioub) {
    int tid = blockIdx.x * blockDim.x + threadIdx.x; // NB*NB threads
    int i = tid >> 10;
    int j = tid & (NB - 1);
    float4 a = bs[i], b = bs[j];
    float ai = (a.z - a.x) * (a.w - a.y);
    float aj = (b.z - b.x) * (b.w - b.y);
    float ix1 = fmaxf(a.x, b.x), iy1 = fmaxf(a.y, b.y);
    float ix2 = fminf(a.z, b.z), iy2 = fminf(a.w, b.w);
    float iw = fmaxf(ix2 - ix1, 0.0f), ih = fmaxf(iy2 - iy1, 0.0f);
    float inter = iw * ih;
    float iou_v = inter / (ai + aj - inter);
    bool bit = iou_v > IOU_T;
    unsigned long long m = __ballot(bit);
    if ((threadIdx.x & 63) == 0) ioub[(size_t)i * 16 + (j >> 6)] = m;
}

// greedy grouping, one thread per start; incompat union mask in LDS.
// Exact check-before-add semantics of the reference scan.
__global__ void __launch_bounds__(128) k_group(const unsigned long long* __restrict__ ioub,
                                               const double* __restrict__ ssd,
                                               const int* __restrict__ counts,
                                               int* recfl, double* recsc,
                                               unsigned long long* recsel) {
    __shared__ unsigned long long inc[128][17];
    __shared__ unsigned long long sel[128][17];
    int t = threadIdx.x;
    int i = blockIdx.x * blockDim.x + t;
    int K = counts[0];
    for (int w = 0; w < 16; w++) {
        inc[t][w] = ioub[(size_t)i * 16 + w];
        sel[t][w] = 0ULL;
    }
    sel[t][i >> 6] = 1ULL << (i & 63);
    int size = 1;
    double score = ssd[i];
    int rec = 0;
    for (int j = i + 1; j < NB; j++) {
        if (size == K) { rec = 1; break; }   // record at TOP of iteration j
        if (!((inc[t][j >> 6] >> (j & 63)) & 1ULL)) {
            sel[t][j >> 6] |= 1ULL << (j & 63);
            size++;
            score += ssd[j];
            const unsigned long long* rj = ioub + (size_t)j * 16;
            for (int w = 0; w < 16; w++) inc[t][w] |= rj[w];
        }
    }
    recfl[i] = rec;
    recsc[i] = rec ? score : -1e300;
    for (int w = 0; w < 16; w++) recsel[(size_t)i * 16 + w] = sel[t][w];
}

// best = max recorded score, ties -> LAST index (reference's last-argmax rule)
__global__ void k_final(const double* __restrict__ recsc,
                        const unsigned long long* __restrict__ recsel,
                        const float* __restrict__ ss32, float* __restrict__ out) {
    __shared__ double bsc[NB];
    __shared__ int bidx[NB];
    int t = threadIdx.x; // 1024 threads
    bsc[t] = recsc[t];
    bidx[t] = t;
    __syncthreads();
    for (int s = 512; s > 0; s >>= 1) {
        if (t < s) {
            double a = bsc[t], b = bsc[t + s];
            if (b > a || (b == a && bidx[t + s] > bidx[t])) {
                bsc[t] = b;
                bidx[t] = bidx[t + s];
            }
        }
        __syncthreads();
    }
    __shared__ int best, any;
    if (t == 0) { best = bidx[0]; any = (bsc[0] > -1e299) ? 1 : 0; }
    __syncthreads();
    float v = 0.0f;
    if (any) {
        if ((recsel[(size_t)best * 16 + (t >> 6)] >> (t & 63)) & 1ULL) v = ss32[t];
    }
    out[t] = v;
}

// ---------------- host entry ------------------------------------------------

extern "C" void kernel_launch(void* const* d_in, const int* in_sizes, int n_in,
                              void* d_out, int out_size, void* d_ws, size_t ws_size,
                              hipStream_t stream) {
    const float* bbox  = (const float*)d_in[0];
    const float* obj   = (const float*)d_in[1];
    const float* probs = (const float*)d_in[2];
    const int*   counts = (const int*)d_in[3];
    float* out = (float*)d_out;

    char* w = (char*)d_ws;
    int4*   coords = (int4*)(w + OFF_COORDS);
    int*    flags  = (int*)(w + OFF_FLAGS);
    int*    slot   = (int*)(w + OFF_SLOT);
    double* part   = (double*)(w + OFF_PART);
    double* sc64   = (double*)(w + OFF_SC64);
    float*  sc32   = (float*)(w + OFF_SC32);
    int*    order  = (int*)(w + OFF_ORDER);
    float4* bs     = (float4*)(w + OFF_BS);
    double* ssd    = (double*)(w + OFF_SSD);
    float*  ss32   = (float*)(w + OFF_SS32);
    unsigned long long* ioub   = (unsigned long long*)(w + OFF_IOU);
    double* recsc  = (double*)(w + OFF_RECSC);
    int*    recfl  = (int*)(w + OFF_RECFL);
    unsigned long long* recsel = (unsigned long long*)(w + OFF_RECSEL);
    float*  Cc     = (float*)(w + OFF_CC);

    k_flags_zero<<<HH / 256, 256, 0, stream>>>(flags);
    k_coords<<<NB / 256, 256, 0, stream>>>(bbox, coords, flags);
    k_scan<<<1, 256, 0, stream>>>(flags, slot);
    k_partials<<<(NCHUNK * WW) / 256, 256, 0, stream>>>(probs, part);
    k_sweep<<<(NCHUNK * WW) / 256, 256, 0, stream>>>(probs, part, flags, slot, Cc);
    k_boxsum<<<NB, 64, 0, stream>>>(coords, obj, slot, Cc, sc64, sc32);
    k_rank<<<NB / 256, 256, 0, stream>>>(sc64, order);
    k_gather<<<NB / 256, 256, 0, stream>>>(order, bbox, sc64, sc32, bs, ssd, ss32);
    k_iou<<<(NB * NB) / 256, 256, 0, stream>>>(bs, ioub);
    k_group<<<NB / 128, 128, 0, stream>>>(ioub, ssd, counts, recfl, recsc, recsel);
    k_final<<<1, 1024, 0, stream>>>(recsc, recsel, ss32, out);
}

// Round 3
// 195.933 us; speedup vs baseline: 4.1578x; 1.2497x over previous
//
#include <hip/hip_runtime.h>

// Problem constants (from reference)
#define HH 4096
#define WW 4096
#define NB 1024
#define NCHUNK 64
#define CROWS 64          // HH / NCHUNK
#define IOU_T 0.5f

// ---------------- workspace layout ------------------------------------------
constexpr size_t OFF_COORDS = 0;                                  // int4 x NB
constexpr size_t OFF_FLAGS  = OFF_COORDS + (size_t)NB * 16;       // int x HH
constexpr size_t OFF_SLOT   = OFF_FLAGS  + (size_t)HH * 4;        // int x HH
constexpr size_t OFF_PART   = OFF_SLOT   + (size_t)HH * 4;        // double x NCHUNK*WW (2 MB)
constexpr size_t OFF_SC64   = OFF_PART   + (size_t)NCHUNK * WW * 8;
constexpr size_t OFF_SC32   = OFF_SC64   + (size_t)NB * 8;
constexpr size_t OFF_ORDER  = OFF_SC32   + (size_t)NB * 4;
constexpr size_t OFF_BS     = OFF_ORDER  + (size_t)NB * 4;        // float4 x NB (sorted boxes)
constexpr size_t OFF_SSD    = OFF_BS     + (size_t)NB * 16;       // double x NB (sorted scores)
constexpr size_t OFF_SS32   = OFF_SSD    + (size_t)NB * 8;        // float x NB
constexpr size_t OFF_IOU    = OFF_SS32   + (size_t)NB * 4;        // u64 x NB*16
constexpr size_t OFF_RECSC  = OFF_IOU    + (size_t)NB * 16 * 8;   // double x NB
constexpr size_t OFF_RECSEL = OFF_RECSC  + (size_t)NB * 8;        // u64 x NB*16
constexpr size_t OFF_CC     = OFF_RECSEL + (size_t)NB * 16 * 8;   // float x 2048*WW (32 MB)
// total ~= 34.4 MB

// ---------------- kernels ---------------------------------------------------

// merged: zero flags + box coords + flag rows + exclusive scan (single block)
__global__ void k_setup(const float* __restrict__ bbox, int4* coords,
                        int* flags, int* slot) {
    __shared__ int lf[HH];      // 16 KB
    __shared__ int psum[256];
    int t = threadIdx.x;
    for (int k = t; k < HH; k += 256) lf[k] = 0;
    __syncthreads();
    for (int i = t; i < NB; i += 256) {
        float b0 = bbox[i * 4 + 0], b1 = bbox[i * 4 + 1];
        float b2 = bbox[i * 4 + 2], b3 = bbox[i * 4 + 3];
        int x1 = min(max((int)floorf(b0), 0), WW);
        int y1 = min(max((int)floorf(b1), 0), HH);
        int x2 = min(max((int)floorf(b2), 0), WW);
        int y2 = min(max((int)floorf(b3), 0), HH);
        coords[i] = make_int4(x1, y1, x2, y2);
        if (y1 >= 1) lf[y1 - 1] = 1;   // benign LDS races: same value
        if (y2 >= 1) lf[y2 - 1] = 1;
    }
    __syncthreads();
    int base = t * 16;
    int s = 0;
    for (int k = 0; k < 16; k++) s += lf[base + k];
    psum[t] = s;
    __syncthreads();
    if (t == 0) {
        int acc = 0;
        for (int k = 0; k < 256; k++) { int v = psum[k]; psum[k] = acc; acc += v; }
    }
    __syncthreads();
    int run = psum[t];
    for (int k = 0; k < 16; k++) {
        flags[base + k] = lf[base + k];
        slot[base + k] = run;
        run += lf[base + k];
    }
}

// fused staging: ONE read of probs. Per (chunk, col-pair) thread: fp64
// within-chunk column cumsum; emit fp32 within-chunk cumsum rows at flagged
// rows; chunk totals -> part (fp64). float2 loads + 4-row unroll for ILP.
__global__ void __launch_bounds__(256) k_stage(const float* __restrict__ probs,
        const int* __restrict__ flags, const int* __restrict__ slot,
        double* __restrict__ part, float* __restrict__ Cc) {
    int tid = blockIdx.x * 256 + threadIdx.x;   // NCHUNK * WW/2 threads
    int c  = tid >> 11;          // chunk (WW/2 == 2048 col-pairs)
    int xg = tid & 2047;         // col-pair index
    const float2* p = (const float2*)(probs + (size_t)c * CROWS * WW) + xg;
    const int* fl = flags + c * CROWS;
    const int* sl = slot  + c * CROWS;
    float2* Cc2 = (float2*)Cc;
    double a0 = 0.0, a1 = 0.0;
    for (int r = 0; r < CROWS; r += 4) {
        float2 p0 = p[(size_t)(r + 0) * (WW / 2)];
        float2 p1 = p[(size_t)(r + 1) * (WW / 2)];
        float2 p2 = p[(size_t)(r + 2) * (WW / 2)];
        float2 p3 = p[(size_t)(r + 3) * (WW / 2)];
        a0 += (double)p0.x; a1 += (double)p0.y;
        if (fl[r + 0]) Cc2[(size_t)sl[r + 0] * (WW / 2) + xg] = make_float2((float)a0, (float)a1);
        a0 += (double)p1.x; a1 += (double)p1.y;
        if (fl[r + 1]) Cc2[(size_t)sl[r + 1] * (WW / 2) + xg] = make_float2((float)a0, (float)a1);
        a0 += (double)p2.x; a1 += (double)p2.y;
        if (fl[r + 2]) Cc2[(size_t)sl[r + 2] * (WW / 2) + xg] = make_float2((float)a0, (float)a1);
        a0 += (double)p3.x; a1 += (double)p3.y;
        if (fl[r + 3]) Cc2[(size_t)sl[r + 3] * (WW / 2) + xg] = make_float2((float)a0, (float)a1);
    }
    ((double2*)part)[(size_t)c * (WW / 2) + xg] = make_double2(a0, a1);
}

// in-place exclusive scan of part along chunk axis (per column), grouped loads
__global__ void k_chunkscan(double* __restrict__ part) {
    int x = blockIdx.x * blockDim.x + threadIdx.x;   // WW threads
    double carry = 0.0;
    for (int g = 0; g < NCHUNK / 16; g++) {
        double v[16];
        #pragma unroll
        for (int k = 0; k < 16; k++) v[k] = part[(size_t)(g * 16 + k) * WW + x];
        #pragma unroll
        for (int k = 0; k < 16; k++) { double tv = v[k]; v[k] = carry; carry += tv; }
        #pragma unroll
        for (int k = 0; k < 16; k++) part[(size_t)(g * 16 + k) * WW + x] = v[k];
    }
}

// per-box rectangle sum: one wave per box; column value = within-chunk fp32
// cumsum row + fp64 chunk prefix. fp64 shuffle-reduce.
__global__ void __launch_bounds__(64) k_boxsum(const int4* __restrict__ coords,
                         const float* __restrict__ obj,
                         const int* __restrict__ slot, const float* __restrict__ Cc,
                         const double* __restrict__ part,
                         double* sc64, float* sc32) {
    int i = blockIdx.x;
    int lane = threadIdx.x;
    int4 cd = coords[i]; // x=x1, y=y1, z=x2, w=y2
    bool h1 = (cd.y >= 1), h2 = (cd.w >= 1);
    const float*  r2 = h2 ? Cc   + (size_t)slot[cd.w - 1] * WW        : Cc;
    const double* q2 = h2 ? part + (size_t)((cd.w - 1) >> 6) * WW     : part;
    const float*  r1 = h1 ? Cc   + (size_t)slot[cd.y - 1] * WW        : Cc;
    const double* q1 = h1 ? part + (size_t)((cd.y - 1) >> 6) * WW     : part;
    double s = 0.0;
    for (int x = cd.x + lane; x < cd.z; x += 64) {
        double v2 = h2 ? ((double)r2[x] + q2[x]) : 0.0;
        double v1 = h1 ? ((double)r1[x] + q1[x]) : 0.0;
        s += (v2 - v1);
    }
    #pragma unroll
    for (int off = 32; off > 0; off >>= 1) s += __shfl_down(s, off);
    if (lane == 0) {
        long long cnt = (long long)(cd.w - cd.y) * (long long)(cd.z - cd.x);
        if (cnt < 1) cnt = 1;
        double box = s / (double)cnt;
        double sc = 0.5 * ((double)obj[i] + box);
        sc64[i] = sc;
        sc32[i] = (float)sc;
    }
}

// stable descending rank sort: rank = #{j : s_j > s_i or (s_j == s_i and j < i)}
__global__ void k_rank(const double* __restrict__ sc64, int* order) {
    __shared__ double s[NB];
    int t = threadIdx.x;
    for (int k = t; k < NB; k += 256) s[k] = sc64[k];
    __syncthreads();
    int i = blockIdx.x * 256 + t;
    double si = s[i];
    int rank = 0;
    for (int j = 0; j < NB; j++) {
        double sj = s[j];
        rank += (sj > si) || (sj == si && j < i);
    }
    order[rank] = i;
}

__global__ void k_gather(const int* __restrict__ order, const float* __restrict__ bbox,
                         const double* __restrict__ sc64, const float* __restrict__ sc32,
                         float4* bs, double* ssd, float* ss32) {
    int i = blockIdx.x * blockDim.x + threadIdx.x;
    if (i >= NB) return;
    int o = order[i];
    bs[i] = ((const float4*)bbox)[o];
    ssd[i] = sc64[o];
    ss32[i] = sc32[o];
}

// IoU(bs_i, bs_j) > 0.5 bit matrix, one u64 word per 64 j's via ballot
__global__ void k_iou(const float4* __restrict__ bs, unsigned long long* __restrict__ ioub) {
    int tid = blockIdx.x * blockDim.x + threadIdx.x; // NB*NB threads
    int i = tid >> 10;
    int j = tid & (NB - 1);
    float4 a = bs[i], b = bs[j];
    float ai = (a.z - a.x) * (a.w - a.y);
    float aj = (b.z - b.x) * (b.w - b.y);
    float ix1 = fmaxf(a.x, b.x), iy1 = fmaxf(a.y, b.y);
    float ix2 = fminf(a.z, b.z), iy2 = fminf(a.w, b.w);
    float iw = fmaxf(ix2 - ix1, 0.0f), ih = fmaxf(iy2 - iy1, 0.0f);
    float inter = iw * ih;
    float iou_v = inter / (ai + aj - inter);
    bool bit = iou_v > IOU_T;
    unsigned long long m = __ballot(bit);
    if ((threadIdx.x & 63) == 0) ioub[(size_t)i * 16 + (j >> 6)] = m;
}

// greedy grouping, one thread per start; incompat union mask in LDS.
// Exact check-before-add semantics of the reference scan. Typical break at
// j ~ i+15 (most pairs compatible, K=10) so the loop is short in practice.
__global__ void __launch_bounds__(128) k_group(const unsigned long long* __restrict__ ioub,
                                               const double* __restrict__ ssd,
                                               const int* __restrict__ counts,
                                               double* recsc,
                                               unsigned long long* recsel) {
    __shared__ unsigned long long inc[128][17];
    __shared__ unsigned long long sel[128][17];
    int t = threadIdx.x;
    int i = blockIdx.x * blockDim.x + t;
    int K = counts[0];
    for (int w = 0; w < 16; w++) {
        inc[t][w] = ioub[(size_t)i * 16 + w];
        sel[t][w] = 0ULL;
    }
    sel[t][i >> 6] = 1ULL << (i & 63);
    int size = 1;
    double score = ssd[i];
    int rec = 0;
    for (int j = i + 1; j < NB; j++) {
        if (size == K) { rec = 1; break; }   // record at TOP of iteration j
        if (!((inc[t][j >> 6] >> (j & 63)) & 1ULL)) {
            sel[t][j >> 6] |= 1ULL << (j & 63);
            size++;
            score += ssd[j];
            const unsigned long long* rj = ioub + (size_t)j * 16;
            for (int w = 0; w < 16; w++) inc[t][w] |= rj[w];
        }
    }
    recsc[i] = rec ? score : -1e300;
    for (int w = 0; w < 16; w++) recsel[(size_t)i * 16 + w] = sel[t][w];
}

// best = max recorded score, ties -> LAST index (reference's last-argmax rule)
__global__ void k_final(const double* __restrict__ recsc,
                        const unsigned long long* __restrict__ recsel,
                        const float* __restrict__ ss32, float* __restrict__ out) {
    __shared__ double bsc[NB];
    __shared__ int bidx[NB];
    int t = threadIdx.x; // 1024 threads
    bsc[t] = recsc[t];
    bidx[t] = t;
    __syncthreads();
    for (int s = 512; s > 0; s >>= 1) {
        if (t < s) {
            double a = bsc[t], b = bsc[t + s];
            if (b > a || (b == a && bidx[t + s] > bidx[t])) {
                bsc[t] = b;
                bidx[t] = bidx[t + s];
            }
        }
        __syncthreads();
    }
    __shared__ int best, any;
    if (t == 0) { best = bidx[0]; any = (bsc[0] > -1e299) ? 1 : 0; }
    __syncthreads();
    float v = 0.0f;
    if (any) {
        if ((recsel[(size_t)best * 16 + (t >> 6)] >> (t & 63)) & 1ULL) v = ss32[t];
    }
    out[t] = v;
}

// ---------------- host entry ------------------------------------------------

extern "C" void kernel_launch(void* const* d_in, const int* in_sizes, int n_in,
                              void* d_out, int out_size, void* d_ws, size_t ws_size,
                              hipStream_t stream) {
    const float* bbox  = (const float*)d_in[0];
    const float* obj   = (const float*)d_in[1];
    const float* probs = (const float*)d_in[2];
    const int*   counts = (const int*)d_in[3];
    float* out = (float*)d_out;

    char* w = (char*)d_ws;
    int4*   coords = (int4*)(w + OFF_COORDS);
    int*    flags  = (int*)(w + OFF_FLAGS);
    int*    slot   = (int*)(w + OFF_SLOT);
    double* part   = (double*)(w + OFF_PART);
    double* sc64   = (double*)(w + OFF_SC64);
    float*  sc32   = (float*)(w + OFF_SC32);
    int*    order  = (int*)(w + OFF_ORDER);
    float4* bs     = (float4*)(w + OFF_BS);
    double* ssd    = (double*)(w + OFF_SSD);
    float*  ss32   = (float*)(w + OFF_SS32);
    unsigned long long* ioub   = (unsigned long long*)(w + OFF_IOU);
    double* recsc  = (double*)(w + OFF_RECSC);
    unsigned long long* recsel = (unsigned long long*)(w + OFF_RECSEL);
    float*  Cc     = (float*)(w + OFF_CC);

    k_setup<<<1, 256, 0, stream>>>(bbox, coords, flags, slot);
    k_stage<<<(NCHUNK * WW / 2) / 256, 256, 0, stream>>>(probs, flags, slot, part, Cc);
    k_chunkscan<<<WW / 256, 256, 0, stream>>>(part);
    k_boxsum<<<NB, 64, 0, stream>>>(coords, obj, slot, Cc, part, sc64, sc32);
    k_rank<<<NB / 256, 256, 0, stream>>>(sc64, order);
    k_gather<<<NB / 256, 256, 0, stream>>>(order, bbox, sc64, sc32, bs, ssd, ss32);
    k_iou<<<(NB * NB) / 256, 256, 0, stream>>>(bs, ioub);
    k_group<<<NB / 128, 128, 0, stream>>>(ioub, ssd, counts, recsc, recsel);
    k_final<<<1, 1024, 0, stream>>>(recsc, recsel, ss32, out);
}